// Round 3
// baseline (1356.255 us; speedup 1.0000x reference)
//
#include <hip/hip_runtime.h>

typedef unsigned short u16;
typedef __attribute__((ext_vector_type(4))) float f32x4;
typedef __attribute__((ext_vector_type(8))) short s16x8;

__device__ __forceinline__ u16 f2bf(float f) {
    union { float f; unsigned u; } c; c.f = f;
    return (u16)((c.u + 0x7fffu + ((c.u >> 16) & 1u)) >> 16);
}
__device__ __forceinline__ float bf2f(u16 u) {
    union { unsigned u; float f; } c; c.u = ((unsigned)u) << 16; return c.f;
}
__device__ __forceinline__ unsigned pk2(float a, float b) {
    return (unsigned)f2bf(a) | ((unsigned)f2bf(b) << 16);
}
__device__ __forceinline__ float sigm(float x) { return 1.0f / (1.0f + __expf(-x)); }

// async global->LDS, 16B/lane; LDS dest = wave-uniform base + lane*16
__device__ __forceinline__ void load16_g2l(const void* g, void* l) {
    __builtin_amdgcn_global_load_lds(
        (const __attribute__((address_space(1))) unsigned int*)(unsigned long long)g,
        (__attribute__((address_space(3))) unsigned int*)(unsigned int)(unsigned long long)l,
        16, 0, 0);
}

// ---- f32 -> bf16 convert, 8 elems/thread -----------------------------------
__global__ __launch_bounds__(256) void convF(const float* __restrict__ in,
                                             u16* __restrict__ out, unsigned n8) {
    unsigned i = blockIdx.x * 256u + threadIdx.x;
    if (i >= n8) return;
    float4 a = ((const float4*)in)[2 * i];
    float4 b = ((const float4*)in)[2 * i + 1];
    uint4 o;
    o.x = pk2(a.x, a.y); o.y = pk2(a.z, a.w);
    o.z = pk2(b.x, b.y); o.w = pk2(b.z, b.w);
    ((uint4*)out)[i] = o;
}

// ---- masked-weight prep: Out_bf16 = (M!=0 ? bf16(W) : 0), 8 elems/thread ---
__global__ __launch_bounds__(256) void maskmulF(const float* __restrict__ W,
                                                const float* __restrict__ Mk,
                                                u16* __restrict__ Out, unsigned n8) {
    unsigned i = blockIdx.x * 256u + threadIdx.x;
    if (i >= n8) return;
    float4 w0 = ((const float4*)W)[2 * i], w1 = ((const float4*)W)[2 * i + 1];
    float4 m0 = ((const float4*)Mk)[2 * i], m1 = ((const float4*)Mk)[2 * i + 1];
    uint4 o;
    o.x = pk2(m0.x != 0.f ? w0.x : 0.f, m0.y != 0.f ? w0.y : 0.f);
    o.y = pk2(m0.z != 0.f ? w0.z : 0.f, m0.w != 0.f ? w0.w : 0.f);
    o.z = pk2(m1.x != 0.f ? w1.x : 0.f, m1.y != 0.f ? w1.y : 0.f);
    o.w = pk2(m1.z != 0.f ? w1.z : 0.f, m1.w != 0.f ? w1.w : 0.f);
    ((uint4*)Out)[i] = o;
}

// ---- idx init (defensive vs ws poison) -------------------------------------
__global__ void init_idx(int* __restrict__ idx) {
    if (threadIdx.x < 128) idx[threadIdx.x] = 0;
}

// ---- one-hot column index extraction: mask [n,32] f32 ----------------------
__global__ __launch_bounds__(256) void find_idx(const float* __restrict__ mask,
                                                int n, int* __restrict__ out) {
    int k = blockIdx.x;  // 0..31
    for (int i = threadIdx.x; i < n; i += 256)
        if (mask[(size_t)i * 32 + k] != 0.0f) out[k] = i;
}

// ---- column gathers --------------------------------------------------------
__global__ __launch_bounds__(256) void gatherF(const float* __restrict__ src, int ld,
                                               const int* __restrict__ idx,
                                               u16* __restrict__ dst, int B) {
    int i = blockIdx.x * 256 + threadIdx.x;
    if (i < B * 32) {
        int b = i >> 5, k = i & 31;
        dst[i] = f2bf(src[(size_t)b * ld + idx[k]]);
    }
}
__global__ __launch_bounds__(256) void gatherB(const u16* __restrict__ src, int ld,
                                               const int* __restrict__ idx,
                                               u16* __restrict__ dst, int B) {
    int i = blockIdx.x * 256 + threadIdx.x;
    if (i < B * 32) {
        int b = i >> 5, k = i & 31;
        dst[i] = src[(size_t)b * ld + idx[k]];
    }
}

// ---- xcat assembly (f32 out) ----------------------------------------------
__global__ __launch_bounds__(256) void build_xcat(float* __restrict__ xcat,
                                                  const u16* __restrict__ x5,
                                                  const u16* __restrict__ kg,
                                                  const u16* __restrict__ ki,
                                                  const u16* __restrict__ kc,
                                                  const u16* __restrict__ kp,
                                                  const float* __restrict__ clinn) {
    int i = blockIdx.x * 256 + threadIdx.x;
    if (i >= 2048 * 400) return;
    int b = i / 400, c = i - b * 400;
    float v;
    if (c < 256)      v = bf2f(x5[b * 256 + c]);
    else if (c < 288) v = bf2f(kg[b * 32 + (c - 256)]);
    else if (c < 320) v = bf2f(ki[b * 32 + (c - 288)]);
    else if (c < 352) v = bf2f(kc[b * 32 + (c - 320)]);
    else if (c < 384) v = bf2f(kp[b * 32 + (c - 352)]);
    else              v = clinn[b * 16 + (c - 384)];
    xcat[i] = v;
}

// ---- m97-style NT GEMM, fused epilogue -------------------------------------
// Out_bf16[m,n] = inv[m,n]*(c1a*c1b)[n] + sigmoid(acc + bias[n]) * (c2a*c2b)[n]
// BM=BN=128, BK=32, 256 thr = 4 waves (2x2 of 64x64), mfma 16x16x32 bf16.
// BMODE 0: W is bf16, async global_load_lds staging.
// BMODE 1: W is f32, VALU convert staging.
// BMODE 2: W,Msk f32, VALU masked-convert staging.
template <int BMODE>
__global__ __launch_bounds__(256) void gemm_bt(const u16* __restrict__ A,
                                               const void* __restrict__ Wv,
                                               const float* __restrict__ Msk,
                                               u16* __restrict__ Out,
                                               const float* __restrict__ bias,
                                               const float* __restrict__ c1a,
                                               const float* __restrict__ c1b,
                                               const float* __restrict__ c2a,
                                               const float* __restrict__ c2b,
                                               const float* __restrict__ inv,
                                               int N, int K) {
    __shared__ u16 At[128 * 32];
    __shared__ u16 Bt[128 * 32];
    const int tid = threadIdx.x;
    const int lane = tid & 63;
    const int wave = tid >> 6;
    const int wrow = wave >> 1, wcol = wave & 1;
    const int tn = blockIdx.x, tm = blockIdx.y;
    const int row = tid >> 2;          // 0..63
    const int kcol = (tid & 3) * 8;    // element offset within BK

    const u16* aS0 = A + (size_t)(tm * 128 + row) * K + kcol;
    const u16* aS1 = aS0 + (size_t)64 * K;
    u16* aD0 = At + wave * 512;
    u16* aD1 = At + 2048 + wave * 512;

    const u16* Wu = (const u16*)Wv;
    const float* Wf = (const float*)Wv;
    const u16* bS0u = (BMODE == 0) ? Wu + (size_t)(tn * 128 + row) * K + kcol : nullptr;
    const u16* bS1u = (BMODE == 0) ? bS0u + (size_t)64 * K : nullptr;
    const float* bS0f = (BMODE != 0) ? Wf + (size_t)(tn * 128 + row) * K + kcol : nullptr;
    const float* bS1f = (BMODE != 0) ? bS0f + (size_t)64 * K : nullptr;
    const float* bM0f = (BMODE == 2) ? Msk + (size_t)(tn * 128 + row) * K + kcol : nullptr;
    const float* bM1f = (BMODE == 2) ? bM0f + (size_t)64 * K : nullptr;
    u16* bD0 = Bt + wave * 512;
    u16* bD1 = Bt + 2048 + wave * 512;
    u16* bW0 = Bt + tid * 8;
    u16* bW1 = Bt + 2048 + tid * 8;

    const int r16 = lane & 15;
    const int q = lane >> 4;
    const u16* aR = At + (wrow * 64 + r16) * 32 + q * 8;
    const u16* bR = Bt + (wcol * 64 + r16) * 32 + q * 8;

    f32x4 acc[4][4];
#pragma unroll
    for (int i = 0; i < 4; i++)
#pragma unroll
        for (int j = 0; j < 4; j++) acc[i][j] = (f32x4){0.f, 0.f, 0.f, 0.f};

    for (int k0 = 0; k0 < K; k0 += 32) {
        load16_g2l(aS0 + k0, aD0);
        load16_g2l(aS1 + k0, aD1);
        if (BMODE == 0) {
            load16_g2l(bS0u + k0, bD0);
            load16_g2l(bS1u + k0, bD1);
        } else {
            float4 w00 = *(const float4*)(bS0f + k0);
            float4 w01 = *(const float4*)(bS0f + k0 + 4);
            float4 w10 = *(const float4*)(bS1f + k0);
            float4 w11 = *(const float4*)(bS1f + k0 + 4);
            if (BMODE == 2) {
                float4 m00 = *(const float4*)(bM0f + k0);
                float4 m01 = *(const float4*)(bM0f + k0 + 4);
                float4 m10 = *(const float4*)(bM1f + k0);
                float4 m11 = *(const float4*)(bM1f + k0 + 4);
                w00.x = m00.x != 0.f ? w00.x : 0.f;  w00.y = m00.y != 0.f ? w00.y : 0.f;
                w00.z = m00.z != 0.f ? w00.z : 0.f;  w00.w = m00.w != 0.f ? w00.w : 0.f;
                w01.x = m01.x != 0.f ? w01.x : 0.f;  w01.y = m01.y != 0.f ? w01.y : 0.f;
                w01.z = m01.z != 0.f ? w01.z : 0.f;  w01.w = m01.w != 0.f ? w01.w : 0.f;
                w10.x = m10.x != 0.f ? w10.x : 0.f;  w10.y = m10.y != 0.f ? w10.y : 0.f;
                w10.z = m10.z != 0.f ? w10.z : 0.f;  w10.w = m10.w != 0.f ? w10.w : 0.f;
                w11.x = m11.x != 0.f ? w11.x : 0.f;  w11.y = m11.y != 0.f ? w11.y : 0.f;
                w11.z = m11.z != 0.f ? w11.z : 0.f;  w11.w = m11.w != 0.f ? w11.w : 0.f;
            }
            uint4 o0, o1;
            o0.x = pk2(w00.x, w00.y); o0.y = pk2(w00.z, w00.w);
            o0.z = pk2(w01.x, w01.y); o0.w = pk2(w01.z, w01.w);
            o1.x = pk2(w10.x, w10.y); o1.y = pk2(w10.z, w10.w);
            o1.z = pk2(w11.x, w11.y); o1.w = pk2(w11.z, w11.w);
            *(uint4*)bW0 = o0;
            *(uint4*)bW1 = o1;
        }
        __syncthreads();
        s16x8 af[4], bfr[4];
#pragma unroll
        for (int mi = 0; mi < 4; mi++) af[mi] = *(const s16x8*)(aR + mi * 512);
#pragma unroll
        for (int ni = 0; ni < 4; ni++) bfr[ni] = *(const s16x8*)(bR + ni * 512);
#pragma unroll
        for (int mi = 0; mi < 4; mi++)
#pragma unroll
            for (int ni = 0; ni < 4; ni++)
                acc[mi][ni] = __builtin_amdgcn_mfma_f32_16x16x32_bf16(af[mi], bfr[ni], acc[mi][ni], 0, 0, 0);
        __syncthreads();
    }

    // epilogue: C/D layout col=lane&15, row=(lane>>4)*4+reg
#pragma unroll
    for (int ni = 0; ni < 4; ni++) {
        const int n = tn * 128 + wcol * 64 + ni * 16 + r16;
        const float bi = bias ? bias[n] : 0.f;
        float c1 = 0.f;
        if (c1a) { c1 = c1a[n]; if (c1b) c1 *= c1b[n]; }
        float c2 = 1.f;
        if (c2a) { c2 = c2a[n]; if (c2b) c2 *= c2b[n]; }
#pragma unroll
        for (int mi = 0; mi < 4; mi++) {
#pragma unroll
            for (int rg = 0; rg < 4; rg++) {
                const int m = tm * 128 + wrow * 64 + mi * 16 + q * 4 + rg;
                float v = sigm(acc[mi][ni][rg] + bi) * c2;
                if (inv) v += inv[(size_t)m * N + n] * c1;
                Out[(size_t)m * N + n] = f2bf(v);
            }
        }
    }
}

// ---- tail: lp = sigmoid(xcat @ W6^T); out = (lp - mean(lp,axis=1)) @ W7^T --
__global__ __launch_bounds__(256) void tail_k(const float* __restrict__ xcat,
                                              const float* __restrict__ W6,
                                              const float* __restrict__ W7,
                                              float* __restrict__ out) {
    __shared__ float xs[8 * 400];
    __shared__ float s1[4][8], s2[4][8], s3[4];
    const int tid = threadIdx.x;
    const int b0 = blockIdx.x * 8;
    for (int i = tid; i < 8 * 400; i += 256) {
        int r = i / 400, k = i - r * 400;
        xs[i] = xcat[(size_t)(b0 + r) * 400 + k];
    }
    __syncthreads();
    const int j = tid;  // output column 0..255
    float acc[8];
#pragma unroll
    for (int r = 0; r < 8; r++) acc[r] = 0.f;
    const float4* wrow = (const float4*)(W6 + (size_t)j * 400);
    for (int c = 0; c < 100; c++) {
        float4 wv = wrow[c];
        const float* wp = (const float*)&wv;
#pragma unroll
        for (int t = 0; t < 4; t++) {
            float w = wp[t];
            int k = c * 4 + t;
#pragma unroll
            for (int r = 0; r < 8; r++) acc[r] += w * xs[r * 400 + k];
        }
    }
    const float w7j = W7[j];
    const int lane = tid & 63, wave = tid >> 6;
    float t3 = w7j;
#pragma unroll
    for (int off = 32; off > 0; off >>= 1) t3 += __shfl_down(t3, off, 64);
    if (lane == 0) s3[wave] = t3;
#pragma unroll
    for (int r = 0; r < 8; r++) {
        float lp = sigm(acc[r]);
        float t1 = lp, t2 = lp * w7j;
#pragma unroll
        for (int off = 32; off > 0; off >>= 1) {
            t1 += __shfl_down(t1, off, 64);
            t2 += __shfl_down(t2, off, 64);
        }
        if (lane == 0) { s1[wave][r] = t1; s2[wave][r] = t2; }
    }
    __syncthreads();
    if (tid < 8) {
        float S1 = s1[0][tid] + s1[1][tid] + s1[2][tid] + s1[3][tid];
        float S2 = s2[0][tid] + s2[1][tid] + s2[2][tid] + s2[3][tid];
        float SW = s3[0] + s3[1] + s3[2] + s3[3];
        out[b0 + tid] = S2 - (S1 * (1.f / 256.f)) * SW;
    }
}

// ---------------------------------------------------------------------------
extern "C" void kernel_launch(void* const* d_in, const int* in_sizes, int n_in,
                              void* d_out, int out_size, void* d_ws, size_t ws_size,
                              hipStream_t stream) {
    const float* x_gene   = (const float*)d_in[0];
    const float* x_invmea = (const float*)d_in[1];
    const float* x_curv   = (const float*)d_in[2];
    const float* clinn    = (const float*)d_in[3];
    const float* Adj      = (const float*)d_in[4];
    const float* edge_m   = (const float*)d_in[5];
    const float* path_m   = (const float*)d_in[6];
    const float* tg_mask  = (const float*)d_in[7];
    const float* ti_mask  = (const float*)d_in[8];
    const float* tc_mask  = (const float*)d_in[9];
    const float* tp_mask  = (const float*)d_in[10];
    const float* W1 = (const float*)d_in[11];  const float* b1 = (const float*)d_in[12];
    const float* W2 = (const float*)d_in[13];  const float* b2 = (const float*)d_in[14];
    const float* W3 = (const float*)d_in[15];  const float* b3 = (const float*)d_in[16];
    const float* W4 = (const float*)d_in[17];  const float* b4 = (const float*)d_in[18];
    const float* W5 = (const float*)d_in[19];  const float* b5 = (const float*)d_in[20];
    const float* W6 = (const float*)d_in[21];
    const float* W7 = (const float*)d_in[22];
    const float* mp11 = (const float*)d_in[23];
    const float* mp12 = (const float*)d_in[24];
    const float* mp1  = (const float*)d_in[25];
    const float* mp21 = (const float*)d_in[26];
    const float* mp22 = (const float*)d_in[27];
    const float* mp2  = (const float*)d_in[28];
    const float* mp3  = (const float*)d_in[29];

    char* ws = (char*)d_ws;
    const float* nulf = nullptr;
    float* out = (float*)d_out;

    // common small-kernel pointers, set per layout below
    u16 *xg, *x1, *x2, *x3, *x4, *x5;
    float* xcat;
    u16 *wm = nullptr, *kg, *ki, *kc, *kp;
    int* idxg;

    enum { BIG, MID, SMALL } mode;
    if (ws_size >= 149000000ull) mode = BIG;
    else if (ws_size >= 59245056ull) mode = MID;
    else mode = SMALL;

    char* kbase;
    if (mode == BIG) {
        wm   = (u16*)(ws + 0);               // 64 MiB masked-weight buffer
        xg   = (u16*)(ws + 67108864);        // 16 MiB
        x1   = (u16*)(ws + 83886080);        // 16 MiB
        x2   = (u16*)(ws + 100663296);       // 32 MiB
        x3   = (u16*)(ws + 134217728);       //  8 MiB
        x4   = (u16*)(ws + 142606336);       //  1 MiB
        x5   = (u16*)(ws + 143654912);       //  1 MiB
        xcat = (float*)(ws + 144703488);     //  3.125 MiB
        kbase = ws + 147980288;
    } else if (mode == MID) {
        x1   = (u16*)(ws + 0);               // 16 MiB; after L2: wm3 zone; after L3: x4/x5/xcat
        x2   = (u16*)(ws + 16777216);        // 32 MiB
        xg   = (u16*)(ws + 16777216);        // aliases x2 (dead before L2 writes)
        wm   = (u16*)(ws + 50331648);        //  8 MiB chunk buffer (L1/L2); L3 uses x1 zone
        x3   = (u16*)(ws + 50331648);        //  8 MiB (after L2; wm zone free during L3)
        x4   = (u16*)(ws + 0);
        x5   = (u16*)(ws + 1048576);
        xcat = (float*)(ws + 2097152);
        kbase = ws + 58720256;
    } else {
        x1   = (u16*)(ws + 0);               // 16 MiB
        x2   = (u16*)(ws + 16777216);        // 32 MiB
        xg   = (u16*)(ws + 16777216);        // aliases x2 (dead before L2)
        x3   = (u16*)(ws + 0);               // over dead x1
        x4   = (u16*)(ws + 8388608);
        x5   = (u16*)(ws + 9437184);
        xcat = (float*)(ws + 10485760);      // 3.125 MiB, ends < 16 MiB
        kbase = ws + 50331648;
    }
    kg = (u16*)(kbase + 0);
    ki = (u16*)(kbase + 131072);
    kc = (u16*)(kbase + 262144);
    kp = (u16*)(kbase + 393216);
    idxg = (int*)(kbase + 524288);
    int* idxi = idxg + 32;
    int* idxc = idxg + 64;
    int* idxp = idxg + 96;

    // ---- small preps ----
    init_idx<<<1, 128, 0, stream>>>(idxg);
    find_idx<<<32, 256, 0, stream>>>(tg_mask, 4096, idxg);
    find_idx<<<32, 256, 0, stream>>>(ti_mask, 4096, idxi);
    find_idx<<<32, 256, 0, stream>>>(tc_mask, 8192, idxc);
    find_idx<<<32, 256, 0, stream>>>(tp_mask, 2048, idxp);
    gatherF<<<256, 256, 0, stream>>>(x_gene, 4096, idxg, kg, 2048);
    convF<<<4096, 256, 0, stream>>>(x_gene, xg, 1048576u);

    // ---- L1: x1 = x_invmea*(mp11*mp1) + sigmoid(xg @ (W1*Adj)^T + b1)*(mp12*mp1)
    if (mode == BIG) {
        maskmulF<<<8192, 256, 0, stream>>>(W1, Adj, wm, 2097152u);
        gemm_bt<0><<<dim3(32, 16), 256, 0, stream>>>(xg, wm, nulf, x1, b1,
                                                     mp11, mp1, mp12, mp1, x_invmea, 4096, 4096);
    } else if (mode == MID) {
        for (int c = 0; c < 4; c++) {
            int n0 = c * 1024;
            maskmulF<<<2048, 256, 0, stream>>>(W1 + (size_t)n0 * 4096, Adj + (size_t)n0 * 4096,
                                               wm, 524288u);
            gemm_bt<0><<<dim3(8, 16), 256, 0, stream>>>(xg, wm, nulf, x1 + n0, b1 + n0,
                                                        mp11 + n0, mp1 + n0, mp12 + n0, mp1 + n0,
                                                        x_invmea + n0, 4096, 4096);
        }
    } else {
        gemm_bt<2><<<dim3(32, 16), 256, 0, stream>>>(xg, W1, Adj, x1, b1,
                                                     mp11, mp1, mp12, mp1, x_invmea, 4096, 4096);
    }
    gatherB<<<256, 256, 0, stream>>>(x1, 4096, idxi, ki, 2048);

    // ---- L2: x2 = x_curv*(mp21*mp2) + sigmoid(x1 @ (W2*edge_m)^T + b2)*(mp22*mp2)
    if (mode == BIG) {
        maskmulF<<<16384, 256, 0, stream>>>(W2, edge_m, wm, 4194304u);
        gemm_bt<0><<<dim3(64, 16), 256, 0, stream>>>(x1, wm, nulf, x2, b2,
                                                     mp21, mp2, mp22, mp2, x_curv, 8192, 4096);
    } else if (mode == MID) {
        for (int c = 0; c < 8; c++) {
            int n0 = c * 1024;
            maskmulF<<<2048, 256, 0, stream>>>(W2 + (size_t)n0 * 4096, edge_m + (size_t)n0 * 4096,
                                               wm, 524288u);
            gemm_bt<0><<<dim3(8, 16), 256, 0, stream>>>(x1, wm, nulf, x2 + n0, b2 + n0,
                                                        mp21 + n0, mp2 + n0, mp22 + n0, mp2 + n0,
                                                        x_curv + n0, 8192, 4096);
        }
    } else {
        gemm_bt<2><<<dim3(64, 16), 256, 0, stream>>>(x1, W2, edge_m, x2, b2,
                                                     mp21, mp2, mp22, mp2, x_curv, 8192, 4096);
    }
    gatherB<<<256, 256, 0, stream>>>(x2, 8192, idxc, kc, 2048);

    // ---- L3: x3 = sigmoid(x2 @ (W3*path_m)^T + b3) * mp3
    if (mode == BIG) {
        maskmulF<<<8192, 256, 0, stream>>>(W3, path_m, wm, 2097152u);
        gemm_bt<0><<<dim3(16, 16), 256, 0, stream>>>(x2, wm, nulf, x3, b3,
                                                     nulf, nulf, mp3, nulf, nulf, 2048, 8192);
    } else if (mode == MID) {
        u16* wm3 = (u16*)(ws + 0);  // x1 zone (dead after ki gather)
        for (int c = 0; c < 2; c++) {
            int n0 = c * 1024;
            maskmulF<<<4096, 256, 0, stream>>>(W3 + (size_t)n0 * 8192, path_m + (size_t)n0 * 8192,
                                               wm3, 1048576u);
            gemm_bt<0><<<dim3(8, 16), 256, 0, stream>>>(x2, wm3, nulf, x3 + n0, b3 + n0,
                                                        nulf, nulf, mp3 + n0, nulf, nulf, 2048, 8192);
        }
    } else {
        gemm_bt<2><<<dim3(16, 16), 256, 0, stream>>>(x2, W3, path_m, x3, b3,
                                                     nulf, nulf, mp3, nulf, nulf, 2048, 8192);
    }
    gatherB<<<256, 256, 0, stream>>>(x3, 2048, idxp, kp, 2048);

    // ---- L4: x4 = sigmoid(x3 @ W4^T + b4) ; W4 f32, VALU-convert staging ----
    gemm_bt<1><<<dim3(2, 16), 256, 0, stream>>>(x3, W4, nulf, x4, b4,
                                                nulf, nulf, nulf, nulf, nulf, 256, 2048);
    // ---- L5: x5 = sigmoid(x4 @ W5^T + b5) -----------------------------------
    gemm_bt<1><<<dim3(2, 16), 256, 0, stream>>>(x4, W5, nulf, x5, b5,
                                                nulf, nulf, nulf, nulf, nulf, 256, 256);

    build_xcat<<<3200, 256, 0, stream>>>(xcat, x5, kg, ki, kc, kp, clinn);
    tail_k<<<256, 256, 0, stream>>>(xcat, W6, W7, out);
}

// Round 4
// 1117.224 us; speedup vs baseline: 1.2140x; 1.2140x over previous
//
#include <hip/hip_runtime.h>

typedef unsigned short u16;
typedef __attribute__((ext_vector_type(4))) float f32x4;
typedef __attribute__((ext_vector_type(8))) short s16x8;

__device__ __forceinline__ u16 f2bf(float f) {
    union { float f; unsigned u; } c; c.f = f;
    return (u16)((c.u + 0x7fffu + ((c.u >> 16) & 1u)) >> 16);
}
__device__ __forceinline__ float bf2f(u16 u) {
    union { unsigned u; float f; } c; c.u = ((unsigned)u) << 16; return c.f;
}
__device__ __forceinline__ unsigned pk2(float a, float b) {
    return (unsigned)f2bf(a) | ((unsigned)f2bf(b) << 16);
}
__device__ __forceinline__ float sigm(float x) { return 1.0f / (1.0f + __expf(-x)); }

// async global->LDS, 16B/lane; LDS dest = wave-uniform base + lane*16
__device__ __forceinline__ void load16_g2l(const void* g, void* l) {
    __builtin_amdgcn_global_load_lds(
        (const __attribute__((address_space(1))) unsigned int*)(unsigned long long)g,
        (__attribute__((address_space(3))) unsigned int*)(unsigned int)(unsigned long long)l,
        16, 0, 0);
}

// ---- f32 -> bf16 convert, 8 elems/thread -----------------------------------
__global__ __launch_bounds__(256) void convF(const float* __restrict__ in,
                                             u16* __restrict__ out, unsigned n8) {
    unsigned i = blockIdx.x * 256u + threadIdx.x;
    if (i >= n8) return;
    float4 a = ((const float4*)in)[2 * i];
    float4 b = ((const float4*)in)[2 * i + 1];
    uint4 o;
    o.x = pk2(a.x, a.y); o.y = pk2(a.z, a.w);
    o.z = pk2(b.x, b.y); o.w = pk2(b.z, b.w);
    ((uint4*)out)[i] = o;
}

// ---- masked-weight prep: Out_bf16 = (M!=0 ? bf16(W) : 0), 8 elems/thread ---
__global__ __launch_bounds__(256) void maskmulF(const float* __restrict__ W,
                                                const float* __restrict__ Mk,
                                                u16* __restrict__ Out, unsigned n8) {
    unsigned i = blockIdx.x * 256u + threadIdx.x;
    if (i >= n8) return;
    float4 w0 = ((const float4*)W)[2 * i], w1 = ((const float4*)W)[2 * i + 1];
    float4 m0 = ((const float4*)Mk)[2 * i], m1 = ((const float4*)Mk)[2 * i + 1];
    uint4 o;
    o.x = pk2(m0.x != 0.f ? w0.x : 0.f, m0.y != 0.f ? w0.y : 0.f);
    o.y = pk2(m0.z != 0.f ? w0.z : 0.f, m0.w != 0.f ? w0.w : 0.f);
    o.z = pk2(m1.x != 0.f ? w1.x : 0.f, m1.y != 0.f ? w1.y : 0.f);
    o.w = pk2(m1.z != 0.f ? w1.z : 0.f, m1.w != 0.f ? w1.w : 0.f);
    ((uint4*)Out)[i] = o;
}

// ---- idx init (defensive vs ws poison) -------------------------------------
__global__ void init_idx(int* __restrict__ idx) {
    if (threadIdx.x < 128) idx[threadIdx.x] = 0;
}

// ---- one-hot column index extraction: mask [n,32] f32 ----------------------
__global__ __launch_bounds__(256) void find_idx(const float* __restrict__ mask,
                                                int n, int* __restrict__ out) {
    int k = blockIdx.x;  // 0..31
    for (int i = threadIdx.x; i < n; i += 256)
        if (mask[(size_t)i * 32 + k] != 0.0f) out[k] = i;
}

// ---- column gathers --------------------------------------------------------
__global__ __launch_bounds__(256) void gatherF(const float* __restrict__ src, int ld,
                                               const int* __restrict__ idx,
                                               u16* __restrict__ dst, int B) {
    int i = blockIdx.x * 256 + threadIdx.x;
    if (i < B * 32) {
        int b = i >> 5, k = i & 31;
        dst[i] = f2bf(src[(size_t)b * ld + idx[k]]);
    }
}
__global__ __launch_bounds__(256) void gatherB(const u16* __restrict__ src, int ld,
                                               const int* __restrict__ idx,
                                               u16* __restrict__ dst, int B) {
    int i = blockIdx.x * 256 + threadIdx.x;
    if (i < B * 32) {
        int b = i >> 5, k = i & 31;
        dst[i] = src[(size_t)b * ld + idx[k]];
    }
}

// ---- xcat assembly (f32 out) ----------------------------------------------
__global__ __launch_bounds__(256) void build_xcat(float* __restrict__ xcat,
                                                  const u16* __restrict__ x5,
                                                  const u16* __restrict__ kg,
                                                  const u16* __restrict__ ki,
                                                  const u16* __restrict__ kc,
                                                  const u16* __restrict__ kp,
                                                  const float* __restrict__ clinn) {
    int i = blockIdx.x * 256 + threadIdx.x;
    if (i >= 2048 * 400) return;
    int b = i / 400, c = i - b * 400;
    float v;
    if (c < 256)      v = bf2f(x5[b * 256 + c]);
    else if (c < 288) v = bf2f(kg[b * 32 + (c - 256)]);
    else if (c < 320) v = bf2f(ki[b * 32 + (c - 288)]);
    else if (c < 352) v = bf2f(kc[b * 32 + (c - 320)]);
    else if (c < 384) v = bf2f(kp[b * 32 + (c - 352)]);
    else              v = clinn[b * 16 + (c - 384)];
    xcat[i] = v;
}

// ---- NT GEMM, 3-slot LDS double-buffer, depth-2 async prefetch -------------
// Out_bf16[m,n] = inv[m,n]*(c1a*c1b)[n] + sigmoid(acc + bias[n]) * (c2a*c2b)[n]
// BM=BN=128, BK=32, 256 thr = 4 waves (2x2 of 64x64), mfma 16x16x32 bf16.
// K-loop: s_waitcnt vmcnt(4) + raw s_barrier (prefetch stays in flight).
__global__ __launch_bounds__(256) void gemm_bt(const u16* __restrict__ A,
                                               const u16* __restrict__ W,
                                               u16* __restrict__ Out,
                                               const float* __restrict__ bias,
                                               const float* __restrict__ c1a,
                                               const float* __restrict__ c1b,
                                               const float* __restrict__ c2a,
                                               const float* __restrict__ c2b,
                                               const float* __restrict__ inv,
                                               int N, int K) {
    __shared__ u16 At[3][128 * 32];
    __shared__ u16 Bt[3][128 * 32];
    const int tid = threadIdx.x;
    const int lane = tid & 63;
    const int wave = tid >> 6;
    const int wrow = wave >> 1, wcol = wave & 1;
    const int tn = blockIdx.x, tm = blockIdx.y;
    const int row = tid >> 2;          // 0..63
    const int kcol = (tid & 3) * 8;    // element offset within BK

    const u16* aS0 = A + (size_t)(tm * 128 + row) * K + kcol;
    const u16* aS1 = aS0 + (size_t)64 * K;
    const u16* bS0 = W + (size_t)(tn * 128 + row) * K + kcol;
    const u16* bS1 = bS0 + (size_t)64 * K;
    const int dOff = wave * 512;       // staging dest offset (elements) within a slot

    const int r16 = lane & 15;
    const int q = lane >> 4;
    const int aOff = (wrow * 64 + r16) * 32 + q * 8;
    const int bOff = (wcol * 64 + r16) * 32 + q * 8;

    const int nIter = K >> 5;

#define ISSUE(slot, it_)                                          \
    do {                                                          \
        const int k0_ = (it_) << 5;                               \
        load16_g2l(aS0 + k0_, &At[slot][dOff]);                   \
        load16_g2l(aS1 + k0_, &At[slot][2048 + dOff]);            \
        load16_g2l(bS0 + k0_, &Bt[slot][dOff]);                   \
        load16_g2l(bS1 + k0_, &Bt[slot][2048 + dOff]);            \
    } while (0)

    ISSUE(0, 0);
    ISSUE(1, 1);

    f32x4 acc[4][4];
#pragma unroll
    for (int i = 0; i < 4; i++)
#pragma unroll
        for (int j = 0; j < 4; j++) acc[i][j] = (f32x4){0.f, 0.f, 0.f, 0.f};

    int sRead = 0;
    for (int it = 0; it < nIter; ++it) {
        // wait until the oldest stage (it) has landed; keep prefetch in flight
        if (it + 1 < nIter) __builtin_amdgcn_s_waitcnt(0xF74);  // vmcnt<=4
        else                __builtin_amdgcn_s_waitcnt(0xF70);  // vmcnt<=0
        __asm__ volatile("" ::: "memory");
        __builtin_amdgcn_s_barrier();
        __asm__ volatile("" ::: "memory");

        const u16* aR = &At[sRead][aOff];
        const u16* bR = &Bt[sRead][bOff];
        s16x8 af[4], bfr[4];
#pragma unroll
        for (int mi = 0; mi < 4; mi++) af[mi] = *(const s16x8*)(aR + mi * 512);
#pragma unroll
        for (int ni = 0; ni < 4; ni++) bfr[ni] = *(const s16x8*)(bR + ni * 512);

        if (it + 2 < nIter) {
            int sW = sRead + 2; if (sW >= 3) sW -= 3;
            ISSUE(sW, it + 2);
        }

#pragma unroll
        for (int mi = 0; mi < 4; mi++)
#pragma unroll
            for (int ni = 0; ni < 4; ni++)
                acc[mi][ni] = __builtin_amdgcn_mfma_f32_16x16x32_bf16(af[mi], bfr[ni], acc[mi][ni], 0, 0, 0);

        sRead = (sRead == 2) ? 0 : sRead + 1;
    }
#undef ISSUE

    // epilogue: C/D layout col=lane&15, row=(lane>>4)*4+reg
#pragma unroll
    for (int ni = 0; ni < 4; ni++) {
        const int n = tn * 128 + wcol * 64 + ni * 16 + r16;
        const float bi = bias ? bias[n] : 0.f;
        float c1 = 0.f;
        if (c1a) { c1 = c1a[n]; if (c1b) c1 *= c1b[n]; }
        float c2 = 1.f;
        if (c2a) { c2 = c2a[n]; if (c2b) c2 *= c2b[n]; }
#pragma unroll
        for (int mi = 0; mi < 4; mi++) {
#pragma unroll
            for (int rg = 0; rg < 4; rg++) {
                const int m = tm * 128 + wrow * 64 + mi * 16 + q * 4 + rg;
                float v = sigm(acc[mi][ni][rg] + bi) * c2;
                if (inv) v += inv[(size_t)m * N + n] * c1;
                Out[(size_t)m * N + n] = f2bf(v);
            }
        }
    }
}

// ---- tail: lp = sigmoid(xcat @ W6^T); out = (lp - mean(lp,axis=1)) @ W7^T --
__global__ __launch_bounds__(256) void tail_k(const float* __restrict__ xcat,
                                              const float* __restrict__ W6,
                                              const float* __restrict__ W7,
                                              float* __restrict__ out) {
    __shared__ float xs[8 * 400];
    __shared__ float s1[4][8], s2[4][8], s3[4];
    const int tid = threadIdx.x;
    const int b0 = blockIdx.x * 8;
    for (int i = tid; i < 8 * 400; i += 256) {
        int r = i / 400, k = i - r * 400;
        xs[i] = xcat[(size_t)(b0 + r) * 400 + k];
    }
    __syncthreads();
    const int j = tid;  // output column 0..255
    float acc[8];
#pragma unroll
    for (int r = 0; r < 8; r++) acc[r] = 0.f;
    const float4* wrow = (const float4*)(W6 + (size_t)j * 400);
    for (int c = 0; c < 100; c++) {
        float4 wv = wrow[c];
        const float* wp = (const float*)&wv;
#pragma unroll
        for (int t = 0; t < 4; t++) {
            float w = wp[t];
            int k = c * 4 + t;
#pragma unroll
            for (int r = 0; r < 8; r++) acc[r] += w * xs[r * 400 + k];
        }
    }
    const float w7j = W7[j];
    const int lane = tid & 63, wave = tid >> 6;
    float t3 = w7j;
#pragma unroll
    for (int off = 32; off > 0; off >>= 1) t3 += __shfl_down(t3, off, 64);
    if (lane == 0) s3[wave] = t3;
#pragma unroll
    for (int r = 0; r < 8; r++) {
        float lp = sigm(acc[r]);
        float t1 = lp, t2 = lp * w7j;
#pragma unroll
        for (int off = 32; off > 0; off >>= 1) {
            t1 += __shfl_down(t1, off, 64);
            t2 += __shfl_down(t2, off, 64);
        }
        if (lane == 0) { s1[wave][r] = t1; s2[wave][r] = t2; }
    }
    __syncthreads();
    if (tid < 8) {
        float S1 = s1[0][tid] + s1[1][tid] + s1[2][tid] + s1[3][tid];
        float S2 = s2[0][tid] + s2[1][tid] + s2[2][tid] + s2[3][tid];
        float SW = s3[0] + s3[1] + s3[2] + s3[3];
        out[b0 + tid] = S2 - (S1 * (1.f / 256.f)) * SW;
    }
}

// ---------------------------------------------------------------------------
extern "C" void kernel_launch(void* const* d_in, const int* in_sizes, int n_in,
                              void* d_out, int out_size, void* d_ws, size_t ws_size,
                              hipStream_t stream) {
    const float* x_gene   = (const float*)d_in[0];
    const float* x_invmea = (const float*)d_in[1];
    const float* x_curv   = (const float*)d_in[2];
    const float* clinn    = (const float*)d_in[3];
    const float* Adj      = (const float*)d_in[4];
    const float* edge_m   = (const float*)d_in[5];
    const float* path_m   = (const float*)d_in[6];
    const float* tg_mask  = (const float*)d_in[7];
    const float* ti_mask  = (const float*)d_in[8];
    const float* tc_mask  = (const float*)d_in[9];
    const float* tp_mask  = (const float*)d_in[10];
    const float* W1 = (const float*)d_in[11];  const float* b1 = (const float*)d_in[12];
    const float* W2 = (const float*)d_in[13];  const float* b2 = (const float*)d_in[14];
    const float* W3 = (const float*)d_in[15];  const float* b3 = (const float*)d_in[16];
    const float* W4 = (const float*)d_in[17];  const float* b4 = (const float*)d_in[18];
    const float* W5 = (const float*)d_in[19];  const float* b5 = (const float*)d_in[20];
    const float* W6 = (const float*)d_in[21];
    const float* W7 = (const float*)d_in[22];
    const float* mp11 = (const float*)d_in[23];
    const float* mp12 = (const float*)d_in[24];
    const float* mp1  = (const float*)d_in[25];
    const float* mp21 = (const float*)d_in[26];
    const float* mp22 = (const float*)d_in[27];
    const float* mp2  = (const float*)d_in[28];
    const float* mp3  = (const float*)d_in[29];

    char* ws = (char*)d_ws;
    const float* nulf = nullptr;
    float* out = (float*)d_out;

    // ws layout (confirmed ws_size >= ~149 MB: BIG mode ran in round 3)
    u16*  wm   = (u16*)(ws + 0);               // 64 MiB masked-weight buffer
    u16*  xg   = (u16*)(ws + 67108864);        // 16 MiB (x_gene bf16; dead after L1)
    u16*  w4b  = (u16*)(ws + 67108864);        //  1 MiB (aliases dead xg, after L1)
    u16*  w5b  = (u16*)(ws + 68157440);        //  256 KiB
    u16*  x1   = (u16*)(ws + 83886080);        // 16 MiB
    u16*  x2   = (u16*)(ws + 100663296);       // 32 MiB
    u16*  x3   = (u16*)(ws + 134217728);       //  8 MiB
    u16*  x4   = (u16*)(ws + 142606336);       //  1 MiB
    u16*  x5   = (u16*)(ws + 143654912);       //  1 MiB
    float* xcat = (float*)(ws + 144703488);    //  3.2 MiB
    char* kbase = ws + 147980288;
    u16* kg = (u16*)(kbase + 0);
    u16* ki = (u16*)(kbase + 131072);
    u16* kc = (u16*)(kbase + 262144);
    u16* kp = (u16*)(kbase + 393216);
    int* idxg = (int*)(kbase + 524288);
    int* idxi = idxg + 32;
    int* idxc = idxg + 64;
    int* idxp = idxg + 96;

    // ---- small preps ----
    init_idx<<<1, 128, 0, stream>>>(idxg);
    find_idx<<<32, 256, 0, stream>>>(tg_mask, 4096, idxg);
    find_idx<<<32, 256, 0, stream>>>(ti_mask, 4096, idxi);
    find_idx<<<32, 256, 0, stream>>>(tc_mask, 8192, idxc);
    find_idx<<<32, 256, 0, stream>>>(tp_mask, 2048, idxp);
    gatherF<<<256, 256, 0, stream>>>(x_gene, 4096, idxg, kg, 2048);
    convF<<<4096, 256, 0, stream>>>(x_gene, xg, 1048576u);

    // ---- L1: x1 = x_invmea*(mp11*mp1) + sigmoid(xg @ (W1*Adj)^T + b1)*(mp12*mp1)
    maskmulF<<<8192, 256, 0, stream>>>(W1, Adj, wm, 2097152u);
    gemm_bt<<<dim3(32, 16), 256, 0, stream>>>(xg, wm, x1, b1,
                                              mp11, mp1, mp12, mp1, x_invmea, 4096, 4096);
    gatherB<<<256, 256, 0, stream>>>(x1, 4096, idxi, ki, 2048);
    // xg now dead: convert W4/W5 into its zone
    convF<<<256, 256, 0, stream>>>(W4, w4b, 65536u);
    convF<<<32, 256, 0, stream>>>(W5, w5b, 8192u);

    // ---- L2: x2 = x_curv*(mp21*mp2) + sigmoid(x1 @ (W2*edge_m)^T + b2)*(mp22*mp2)
    maskmulF<<<16384, 256, 0, stream>>>(W2, edge_m, wm, 4194304u);
    gemm_bt<<<dim3(64, 16), 256, 0, stream>>>(x1, wm, x2, b2,
                                              mp21, mp2, mp22, mp2, x_curv, 8192, 4096);
    gatherB<<<256, 256, 0, stream>>>(x2, 8192, idxc, kc, 2048);

    // ---- L3: x3 = sigmoid(x2 @ (W3*path_m)^T + b3) * mp3
    maskmulF<<<8192, 256, 0, stream>>>(W3, path_m, wm, 2097152u);
    gemm_bt<<<dim3(16, 16), 256, 0, stream>>>(x2, wm, x3, b3,
                                              nulf, nulf, mp3, nulf, nulf, 2048, 8192);
    gatherB<<<256, 256, 0, stream>>>(x3, 2048, idxp, kp, 2048);

    // ---- L4: x4 = sigmoid(x3 @ W4^T + b4) ----
    gemm_bt<<<dim3(2, 16), 256, 0, stream>>>(x3, w4b, x4, b4,
                                             nulf, nulf, nulf, nulf, nulf, 256, 2048);
    // ---- L5: x5 = sigmoid(x4 @ W5^T + b5) ----
    gemm_bt<<<dim3(2, 16), 256, 0, stream>>>(x4, w5b, x5, b5,
                                             nulf, nulf, nulf, nulf, nulf, 256, 256);

    build_xcat<<<3200, 256, 0, stream>>>(xcat, x5, kg, ki, kc, kp, clinn);
    tail_k<<<256, 256, 0, stream>>>(xcat, W6, W7, out);
}